// Round 15
// baseline (17.440 us; speedup 1.0000x reference)
//
#include <hip/hip_runtime.h>
#include <hip/hip_bf16.h>
#include <math.h>

// HyperbolicDistanceHead: out[r][c] = -(2/sqrt(c))*atanh(clip(sqrt(c)*||mobius(-x,p)||, 0, 1-1e-5))
// B=128, C=4096, D=1024, c=0.5.  Single launch, no workspace, ONE barrier.
// 256 blocks x 256 thr (1/CU); block = 32 rows x 64 cols; wave = 32x16 full-K.
// p NEVER touches LDS: streamed global->reg in B-fragment order (lane=col l&15,
// k-run g*8; r3-validated mapping), cvt'd in-reg, 4-deep static prefetch (pbuf[4],
// full unroll -> rule-20-safe).  x staged whole-K bf16 in LDS once (64 KB, XOR-swz).
// Exact fp32 x2 (pre-cvt, LDS) and p2 (in-stream, register-only via shfl).
// XCD swizzle: 4 row-group blocks of a col-group co-XCD -> p L2-served after 1st.

#define DDIM 1024
#define CDIM 4096

using f32x4  = __attribute__((ext_vector_type(4))) float;
using bf16x8 = __attribute__((ext_vector_type(8))) short;

__device__ inline ushort toBfU(float f) {
  __hip_bfloat16 h = __float2bfloat16(f);
  return *reinterpret_cast<ushort*>(&h);
}

__global__ __launch_bounds__(256) void hyper_pstream(
    const float* __restrict__ x, const float* __restrict__ p,
    float* __restrict__ out) {
  __shared__ __align__(16) char xs[32 * 2048];   // 64 KB: [row][1024 bf16], XOR-swz
  __shared__ float x2s[32];

  const int tid  = threadIdx.x;
  const int lane = tid & 63;
  const int w    = __builtin_amdgcn_readfirstlane(tid >> 6);  // 0..3
  const int r15  = lane & 15, g = lane >> 4;

  // bijective XCD chunk swizzle (256 % 8 == 0): 32 consecutive per XCD
  const int bid  = blockIdx.x;
  const int swz  = ((bid & 7) << 5) | (bid >> 3);
  const int cg   = swz >> 2, rg = swz & 3;       // 64-col group, 32-row group
  const int rbase = rg * 32, cbase = cg * 64;

  // ---- x staging map: thread -> row tr, 16-float runs at l8*16 + m*128
  const int tr = tid >> 3, l8 = tid & 7;
  const float* gx = x + (size_t)(rbase + tr) * DDIM + l8 * 16;
  const int xsw = (tr & 7) << 4;

  float sx = 0.f;
  #pragma unroll
  for (int m = 0; m < 8; ++m) {
    f32x4 v0 = *(const f32x4*)(gx + m * 128);
    f32x4 v1 = *(const f32x4*)(gx + m * 128 + 4);
    f32x4 v2 = *(const f32x4*)(gx + m * 128 + 8);
    f32x4 v3 = *(const f32x4*)(gx + m * 128 + 12);
    sx = fmaf(v0[0],v0[0],sx); sx = fmaf(v0[1],v0[1],sx);
    sx = fmaf(v0[2],v0[2],sx); sx = fmaf(v0[3],v0[3],sx);
    sx = fmaf(v1[0],v1[0],sx); sx = fmaf(v1[1],v1[1],sx);
    sx = fmaf(v1[2],v1[2],sx); sx = fmaf(v1[3],v1[3],sx);
    sx = fmaf(v2[0],v2[0],sx); sx = fmaf(v2[1],v2[1],sx);
    sx = fmaf(v2[2],v2[2],sx); sx = fmaf(v2[3],v2[3],sx);
    sx = fmaf(v3[0],v3[0],sx); sx = fmaf(v3[1],v3[1],sx);
    sx = fmaf(v3[2],v3[2],sx); sx = fmaf(v3[3],v3[3],sx);
    bf16x8 wlo, whi;
    wlo[0]=(short)toBfU(v0[0]); wlo[1]=(short)toBfU(v0[1]);
    wlo[2]=(short)toBfU(v0[2]); wlo[3]=(short)toBfU(v0[3]);
    wlo[4]=(short)toBfU(v1[0]); wlo[5]=(short)toBfU(v1[1]);
    wlo[6]=(short)toBfU(v1[2]); wlo[7]=(short)toBfU(v1[3]);
    whi[0]=(short)toBfU(v2[0]); whi[1]=(short)toBfU(v2[1]);
    whi[2]=(short)toBfU(v2[2]); whi[3]=(short)toBfU(v2[3]);
    whi[4]=(short)toBfU(v3[0]); whi[5]=(short)toBfU(v3[1]);
    whi[6]=(short)toBfU(v3[2]); whi[7]=(short)toBfU(v3[3]);
    const int kb = m * 256 + l8 * 32;          // logical byte offset in row
    *(bf16x8*)&xs[tr * 2048 + ((kb)      ^ xsw)] = wlo;
    *(bf16x8*)&xs[tr * 2048 + ((kb + 16) ^ xsw)] = whi;
  }
  // exact x2: 8 consecutive lanes share a row
  sx += __shfl_xor(sx, 1, 64);
  sx += __shfl_xor(sx, 2, 64);
  sx += __shfl_xor(sx, 4, 64);
  if ((lane & 7) == 0) x2s[tr] = sx;

  // ---- p-stream setup: wave w owns cols cbase + w*16 .. +15; lane = col r15, k-run g*8
  const float* gp = p + (size_t)(cbase + w * 16 + r15) * DDIM + g * 8;
  f32x4 pb[4][2];                               // 4-step prefetch ring (static idx)
  #pragma unroll
  for (int kk = 0; kk < 4; ++kk) {
    pb[kk][0] = *(const f32x4*)(gp + kk * 32);
    pb[kk][1] = *(const f32x4*)(gp + kk * 32 + 4);
  }

  __syncthreads();   // THE barrier: publishes xs + x2s

  // ---- main: 32 fully-unrolled steps; no sync, no LDS writes, prefetch 4 ahead
  const int a0base = r15 * 2048;
  const int a1base = (16 + r15) * 2048;
  const int aswz0  = (r15 & 7) << 4;
  f32x4 acc0 = {0.f,0.f,0.f,0.f}, acc1 = {0.f,0.f,0.f,0.f};
  float p2p = 0.f;

  #pragma unroll
  for (int kk = 0; kk < 32; ++kk) {
    const f32x4 q0 = pb[kk & 3][0], q1 = pb[kk & 3][1];
    p2p = fmaf(q0[0],q0[0],p2p); p2p = fmaf(q0[1],q0[1],p2p);
    p2p = fmaf(q0[2],q0[2],p2p); p2p = fmaf(q0[3],q0[3],p2p);
    p2p = fmaf(q1[0],q1[0],p2p); p2p = fmaf(q1[1],q1[1],p2p);
    p2p = fmaf(q1[2],q1[2],p2p); p2p = fmaf(q1[3],q1[3],p2p);
    bf16x8 bb;
    bb[0]=(short)toBfU(q0[0]); bb[1]=(short)toBfU(q0[1]);
    bb[2]=(short)toBfU(q0[2]); bb[3]=(short)toBfU(q0[3]);
    bb[4]=(short)toBfU(q1[0]); bb[5]=(short)toBfU(q1[1]);
    bb[6]=(short)toBfU(q1[2]); bb[7]=(short)toBfU(q1[3]);
    if (kk < 28) {
      pb[kk & 3][0] = *(const f32x4*)(gp + (kk + 4) * 32);
      pb[kk & 3][1] = *(const f32x4*)(gp + (kk + 4) * 32 + 4);
    }
    const int ko = kk * 64 + g * 16;
    const bf16x8 a0 = *(const bf16x8*)&xs[a0base + (ko ^ aswz0)];
    const bf16x8 a1 = *(const bf16x8*)&xs[a1base + (ko ^ aswz0)];
    acc0 = __builtin_amdgcn_mfma_f32_16x16x32_bf16(a0, bb, acc0, 0, 0, 0);
    acc1 = __builtin_amdgcn_mfma_f32_16x16x32_bf16(a1, bb, acc1, 0, 0, 0);
  }

  // ---- p2: 4 lanes (l, l^16, l^32, l^48) share a col; register-only reduce
  p2p += __shfl_xor(p2p, 16, 64);
  p2p += __shfl_xor(p2p, 32, 64);
  const float p2 = p2p;                          // every lane: its col's exact p2

  // ---- epilogue: closed-form Poincare distance, c = 0.5
  #pragma unroll
  for (int i = 0; i < 4; ++i) {
    // C-frag: col = lane&15, row = (lane>>4)*4 + i (verified m89 mapping)
    #pragma unroll
    for (int f = 0; f < 2; ++f) {
      const int  rloc = f * 16 + (g << 2) + i;   // block-local row
      const float dot = f ? acc1[i] : acc0[i];   // <x,p>; mdot = -dot
      const float x2  = x2s[rloc];
      const float A   = 1.0f - dot + 0.5f  * p2; // 1 + 2c*mdot + c*p2
      const float Bc  = 1.0f - 0.5f * x2;        // 1 - c*x2
      const float den = 1.0f - dot + 0.25f * x2 * p2;
      float num2 = A * A * x2 - 2.0f * A * Bc * dot + Bc * Bc * p2;
      float m2   = fmaxf(num2, 0.0f) / fmaxf(den * den, 1e-15f);
      float arg  = fminf(0.7071067811865476f * sqrtf(m2 + 1e-15f), 0.99999f);
      out[(size_t)(rbase + rloc) * CDIM + cbase + w * 16 + r15] =
          -1.4142135623730951f * __logf((1.0f + arg) / (1.0f - arg));
    }
  }
}

extern "C" void kernel_launch(void* const* d_in, const int* in_sizes, int n_in,
                              void* d_out, int out_size, void* d_ws, size_t ws_size,
                              hipStream_t stream) {
  const float* x = (const float*)d_in[0];   // [128,1024] fp32
  const float* p = (const float*)d_in[1];   // [4096,1024] fp32
  float* out = (float*)d_out;               // [128,4096] fp32
  hyper_pstream<<<dim3(256), dim3(256), 0, stream>>>(x, p, out);
}